// Round 13
// baseline (304.882 us; speedup 1.0000x reference)
//
#include <hip/hip_runtime.h>
#include <hip/hip_bf16.h>

typedef __attribute__((ext_vector_type(8))) short bf16x8;
typedef __attribute__((ext_vector_type(4))) float f32x4;
typedef unsigned short u16;
typedef unsigned int u32;

constexpr int B = 2, S = 2048, D = 2048, H = 16, HD = 128, ROT = 64;
constexpr int NQKV = 3 * D;  // 6144

__device__ __forceinline__ void gload16(const u16* g, u16* l)
{
    __builtin_amdgcn_global_load_lds((const __attribute__((address_space(1))) void*)g,
                                     (__attribute__((address_space(3))) void*)l, 16, 0, 0);
}

__device__ __forceinline__ float bf2f(u32 lo16) { return __uint_as_float(lo16 << 16); }

// ---------------- fused prep: casts + rope table + keep/expo + counts ----------------
__global__ void fused_prep(const float* __restrict__ hs,
                           const float* __restrict__ Wq, const float* __restrict__ Wk,
                           const float* __restrict__ Wv, const float* __restrict__ Wo,
                           const float* __restrict__ mask, const int* __restrict__ pos,
                           const float* __restrict__ ncst,
                           u16* __restrict__ hs16, u16* __restrict__ wqkv16, u16* __restrict__ wo16,
                           float2* __restrict__ sc2, float* __restrict__ keep,
                           float* __restrict__ expo, float* __restrict__ counts)
{
    int bid = blockIdx.x, tid = threadIdx.x;
    if (bid < 1024) {
        const int total = 2097152 + 4 * 1048576;
        int idx = bid * 256 + tid;
        int stride = 1024 * 256;
        for (int i = idx; i < total; i += stride) {
            const float* src; u16* dst; int off;
            if (i < 2097152) { src = hs; dst = hs16; off = i; }
            else {
                int j = i - 2097152;
                int wsel = j >> 20; off = j & 1048575;
                src = wsel == 0 ? Wq : wsel == 1 ? Wk : wsel == 2 ? Wv : Wo;
                dst = wsel < 3 ? wqkv16 + (size_t)wsel * D * D : wo16;
            }
            float4 v = ((const float4*)src)[off];
            __hip_bfloat16 a = __float2bfloat16(v.x);
            __hip_bfloat16 b = __float2bfloat16(v.y);
            __hip_bfloat16 c = __float2bfloat16(v.z);
            __hip_bfloat16 d = __float2bfloat16(v.w);
            ushort4 o;
            o.x = *(u16*)&a; o.y = *(u16*)&b; o.z = *(u16*)&c; o.w = *(u16*)&d;
            ((ushort4*)dst)[off] = o;
        }
    } else if (bid < 1536) {
        int gid = (bid - 1024) * 256 + tid;
        int j = gid & 31;
        int bs = gid >> 5;
        float p = (float)pos[bs];
        float f = powf(10000.f, -(float)j / 32.f);
        float ang = p * f;
        sc2[gid] = make_float2(cosf(ang), sinf(ang));
        if (j == 0) keep[bs] = (mask[bs] == 0.f) ? 1.f : 0.f;
        if (gid < H) expo[gid] = 1.f / (1.f + expf(-ncst[gid]));
    } else {
        __shared__ float part[256];
        int b = bid - 1536, t = tid;
        float v[8];
        float s = 0.f;
        const float* mp = mask + b * S + t * 8;
#pragma unroll
        for (int i = 0; i < 8; ++i) { s += (mp[i] == 0.f) ? 1.f : 0.f; v[i] = s; }
        part[t] = s;
        __syncthreads();
        float off = 0.f;
        for (int j = 0; j < t; ++j) off += part[j];
        float* cp = counts + b * S + t * 8;
#pragma unroll
        for (int i = 0; i < 8; ++i) cp[i] = off + v[i];
    }
}

// =======================================================================
// BK=64 tiled bf16 B^T GEMM: double-buffered, prefetch-1 burst, counted
// vmcnt(CA+CB), 2 barriers/tile. 128B rows -> 8-slot XOR swizzle
// (slot16 ^= row&7) on BOTH pre-swizzled source and ds_read (rule 21).
// =======================================================================

template <int CNT>
__device__ __forceinline__ void stage64(const u16* __restrict__ G, int K,
                                        int trow0, int kt, u16* lbuf, int tid)
{
#pragma unroll
    for (int l = 0; l < CNT; ++l) {
        int idx = l * 512 + tid;
        int row = idx >> 3;
        int slot = idx & 7;
        int col8 = slot ^ (row & 7);  // inverse-swizzled source
        const u16* g = G + (size_t)(trow0 + row) * K + kt * 64 + col8 * 8;
        u16* ld = lbuf + (size_t)(idx & ~63) * 8;  // wave-uniform base + lane*16B
        gload16(g, ld);
    }
}

template <int BM, int BN, int CA, int CB, int MR, int NR, int BF16OUT>
__global__ __launch_bounds__(512, 1) void gemm64(
    const u16* __restrict__ A, const u16* __restrict__ Bm,
    float* __restrict__ Cf, u16* __restrict__ Cb, int N, int K, int ntn)
{
    __shared__ u16 As[2 * BM * 64];
    __shared__ u16 Bs[2 * BN * 64];
    const int tid = threadIdx.x;
    const int lane = tid & 63;
    const int w = tid >> 6;
    const int wm = w >> 2;      // 0..1
    const int wn = w & 3;       // 0..3
    const int l15 = lane & 15, l4 = lane >> 4;

    // bijective XCD-aware swizzle (nwg % 8 == 0)
    int nwg = gridDim.x;
    int bid = blockIdx.x;
    int cpx = nwg >> 3;
    int sbid = (bid & 7) * cpx + (bid >> 3);
    int bm = sbid / ntn, bn = sbid % ntn;
    const int bmrow = bm * BM, bnrow = bn * BN;

    f32x4 acc[MR][NR] = {};
    const int nk = K >> 6;

    stage64<CA>(A, K, bmrow, 0, &As[0], tid);
    stage64<CB>(Bm, K, bnrow, 0, &Bs[0], tid);

    for (int t = 0; t < nk; ++t) {
        const u16* ab = &As[(t & 1) * BM * 64];
        const u16* bb = &Bs[(t & 1) * BN * 64];
        if (t + 1 < nk) {
            stage64<CA>(A, K, bmrow, t + 1, &As[((t + 1) & 1) * BM * 64], tid);
            stage64<CB>(Bm, K, bnrow, t + 1, &Bs[((t + 1) & 1) * BN * 64], tid);
            asm volatile("s_waitcnt vmcnt(%0)" :: "i"(CA + CB) : "memory");
        } else {
            asm volatile("s_waitcnt vmcnt(0)" ::: "memory");
        }
        __builtin_amdgcn_sched_barrier(0);
        __builtin_amdgcn_s_barrier();  // tile t resident for all waves

#pragma unroll
        for (int tt = 0; tt < 2; ++tt) {
            bf16x8 af[MR];
#pragma unroll
            for (int i = 0; i < MR; ++i) {
                int row = wm * (BM / 2) + i * 16 + l15;
                int slot = (tt * 4 + l4) ^ (row & 7);
                af[i] = *(const bf16x8*)(ab + row * 64 + slot * 8);
            }
#pragma unroll
            for (int n = 0; n < NR; ++n) {
                int brow = wn * (BN / 4) + n * 16 + l15;
                int bslot = (tt * 4 + l4) ^ (brow & 7);
                bf16x8 bf = *(const bf16x8*)(bb + brow * 64 + bslot * 8);
                __builtin_amdgcn_s_setprio(1);
#pragma unroll
                for (int i = 0; i < MR; ++i)
                    acc[i][n] = __builtin_amdgcn_mfma_f32_16x16x32_bf16(af[i], bf, acc[i][n], 0, 0, 0);
                __builtin_amdgcn_s_setprio(0);
            }
        }
        __builtin_amdgcn_sched_barrier(0);
        __builtin_amdgcn_s_barrier();  // all reads done before next-iter stages
    }

    // epilogue
#pragma unroll
    for (int i = 0; i < MR; ++i) {
        int row = bmrow + wm * (BM / 2) + i * 16 + l4 * 4;
#pragma unroll
        for (int n = 0; n < NR; ++n) {
            int col = bnrow + wn * (BN / 4) + n * 16 + l15;
            f32x4 v = acc[i][n];
#pragma unroll
            for (int r = 0; r < 4; ++r) {
                if (BF16OUT) {
                    __hip_bfloat16 hv = __float2bfloat16(v[r]);
                    Cb[(size_t)(row + r) * N + col] = *(u16*)&hv;
                } else {
                    Cf[(size_t)(row + r) * N + col] = v[r];
                }
            }
        }
    }
}

// ---------------- fused postproc: RoPE + norm (q,k), count-scale (v) ----------------
__global__ void postproc_all(const u16* __restrict__ tmpb,
                             u16* __restrict__ qn, u16* __restrict__ kn, u16* __restrict__ vr,
                             const float2* __restrict__ sc2,
                             const float* __restrict__ keep, const float* __restrict__ counts,
                             const float* __restrict__ expo)
{
    int gw = (blockIdx.x * blockDim.x + threadIdx.x) >> 6;
    int lane = threadIdx.x & 63;
    if (gw >= B * S * H) return;
    int h = gw % H;
    int sb = gw / H;
    int s = sb % S;
    int b = sb / S;
    const u16* rowp = tmpb + (size_t)(b * S + s) * NQKV;
    u32 qv = *(const u32*)(rowp + h * 128 + lane * 2);
    u32 kv = *(const u32*)(rowp + D + h * 128 + lane * 2);
    u32 vv = *(const u32*)(rowp + 2 * D + h * 128 + lane * 2);
    float q0 = bf2f(qv & 0xffff), q1 = bf2f(qv >> 16);
    float k0 = bf2f(kv & 0xffff), k1 = bf2f(kv >> 16);
    float v0 = bf2f(vv & 0xffff), v1 = bf2f(vv >> 16);
    if (lane < 32) {
        float2 cs = sc2[(b * S + s) * 32 + lane];
        float nq0 = q0 * cs.x - q1 * cs.y, nq1 = q1 * cs.x + q0 * cs.y;
        float nk0 = k0 * cs.x - k1 * cs.y, nk1 = k1 * cs.x + k0 * cs.y;
        q0 = nq0; q1 = nq1; k0 = nk0; k1 = nk1;
    }
    float sq = q0 * q0 + q1 * q1;
    float sk = k0 * k0 + k1 * k1;
#pragma unroll
    for (int o = 1; o < 64; o <<= 1) {
        sq += __shfl_xor(sq, o, 64);
        sk += __shfl_xor(sk, o, 64);
    }
    float kf = keep[b * S + s];
    float scq = kf / fmaxf(sqrtf(sq), 1e-12f);
    float sck = kf / fmaxf(sqrtf(sk), 1e-12f);
    float cnt = counts[b * S + s];
    float e = expo[h];
    float scv = kf / fmaxf(powf(cnt, e), 1.0f);

    __hip_bfloat16 a0 = __float2bfloat16(q0 * scq), a1 = __float2bfloat16(q1 * scq);
    __hip_bfloat16 b0 = __float2bfloat16(k0 * sck), b1 = __float2bfloat16(k1 * sck);
    __hip_bfloat16 c0 = __float2bfloat16(v0 * scv), c1 = __float2bfloat16(v1 * scv);
    size_t obase = ((size_t)(b * H + h) * S + s) * 128 + lane * 2;
    *(u32*)(qn + obase) = (u32)*(u16*)&a0 | ((u32)*(u16*)&a1 << 16);
    *(u32*)(kn + obase) = (u32)*(u16*)&b0 | ((u32)*(u16*)&b1 << 16);
    *(u32*)(vr + obase) = (u32)*(u16*)&c0 | ((u32)*(u16*)&c1 << 16);
}

// ---------------- chunk state: T_c[d][d'] = sum_{k in chunk} v[k,d] * kn[k,d'] ----------------
__global__ __launch_bounds__(256) void chunk_state(
    const u16* __restrict__ kn, const u16* __restrict__ vr, u16* __restrict__ T16)
{
    __shared__ u16 As[128][72];
    __shared__ u16 Bs[128][72];
    int tid = threadIdx.x, lane = tid & 63, w = tid >> 6;
    int wm = w >> 1, wn = w & 1;
    int c = blockIdx.x, bh = blockIdx.y;
    const int l15 = lane & 15, l4 = lane >> 4;
    size_t base = (size_t)bh * S * 128;
    f32x4 acc[4][4] = {};

    for (int t = 0; t < 2; ++t) {
#pragma unroll
        for (int i = 0; i < 4; ++i) {
            int q = tid + i * 256;
            int r = q >> 4, c16 = q & 15;
            uint4 v = *(const uint4*)(vr + base + (size_t)(c * 128 + t * 64 + r) * 128 + c16 * 8);
            const u16* pv = (const u16*)&v;
#pragma unroll
            for (int j = 0; j < 8; ++j) As[c16 * 8 + j][r] = pv[j];
        }
#pragma unroll
        for (int i = 0; i < 4; ++i) {
            int q = tid + i * 256;
            int r = q >> 4, c16 = q & 15;
            uint4 v = *(const uint4*)(kn + base + (size_t)(c * 128 + t * 64 + r) * 128 + c16 * 8);
            const u16* pv = (const u16*)&v;
#pragma unroll
            for (int j = 0; j < 8; ++j) Bs[c16 * 8 + j][r] = pv[j];
        }
        __syncthreads();
#pragma unroll
        for (int tt = 0; tt < 2; ++tt) {
            bf16x8 a[4], b[4];
#pragma unroll
            for (int m = 0; m < 4; ++m)
                a[m] = *(const bf16x8*)(&As[wm * 64 + m * 16 + l15][tt * 32 + l4 * 8]);
#pragma unroll
            for (int n = 0; n < 4; ++n)
                b[n] = *(const bf16x8*)(&Bs[wn * 64 + n * 16 + l15][tt * 32 + l4 * 8]);
#pragma unroll
            for (int m = 0; m < 4; ++m)
#pragma unroll
                for (int n = 0; n < 4; ++n)
                    acc[m][n] = __builtin_amdgcn_mfma_f32_16x16x32_bf16(a[m], b[n], acc[m][n], 0, 0, 0);
        }
        __syncthreads();
    }
#pragma unroll
    for (int m = 0; m < 4; ++m) {
        int row = wm * 64 + m * 16 + l4 * 4;
#pragma unroll
        for (int n = 0; n < 4; ++n) {
            int col = wn * 64 + n * 16 + l15;
#pragma unroll
            for (int r = 0; r < 4; ++r) {
                __hip_bfloat16 hv = __float2bfloat16(acc[m][n][r]);
                T16[((size_t)(bh * 16 + c) * 128 + row + r) * 128 + col] = *(u16*)&hv;
            }
        }
    }
}

// ---------------- exclusive prefix over chunks ----------------
__global__ void prefix_state(const u16* __restrict__ T16, u16* __restrict__ P16)
{
    int g = blockIdx.x * blockDim.x + threadIdx.x;
    int bh = g >> 11;
    int i8 = (g & 2047) * 8;
    const u16* tp = T16 + (size_t)bh * 16 * 16384 + i8;
    u16* pp = P16 + (size_t)bh * 16 * 16384 + i8;
    float run[8] = {};
    for (int c = 0; c < 16; ++c) {
        u16 ob[8];
#pragma unroll
        for (int j = 0; j < 8; ++j) { __hip_bfloat16 hv = __float2bfloat16(run[j]); ob[j] = *(u16*)&hv; }
        *(uint4*)(pp + (size_t)c * 16384) = *(uint4*)ob;
        uint4 tv = *(const uint4*)(tp + (size_t)c * 16384);
        const u16* tvp = (const u16*)&tv;
#pragma unroll
        for (int j = 0; j < 8; ++j) run[j] += bf2f(tvp[j]);
    }
}

// ---------------- chunked attention: out_c = qn_c . P_c + causal_intra ----------------
__global__ __launch_bounds__(256, 2) void attn2(
    const u16* __restrict__ qn, const u16* __restrict__ kn,
    const u16* __restrict__ vr, const u16* __restrict__ P16, u16* __restrict__ ao)
{
    __shared__ u16 KN[64][136];
    __shared__ u16 VT[128][72];
    __shared__ u16 SC[128][72];
    int tid = threadIdx.x, lane = tid & 63, w = tid >> 6;
    int c = blockIdx.x, bh = blockIdx.y;
    int b = bh >> 4, h = bh & 15;
    const int l15 = lane & 15, l4 = lane >> 4;
    size_t base = (size_t)bh * S * 128;
    const u16* Pp = P16 + (size_t)(bh * 16 + c) * 16384;

    bf16x8 qa[2][4];
#pragma unroll
    for (int m = 0; m < 2; ++m)
#pragma unroll
        for (int t = 0; t < 4; ++t) {
            int row = c * 128 + w * 32 + m * 16 + l15;
            qa[m][t] = *(const bf16x8*)(qn + base + (size_t)row * 128 + t * 32 + l4 * 8);
        }

    f32x4 acc[2][8] = {};

#pragma unroll
    for (int pt = 0; pt < 2; ++pt) {
#pragma unroll
        for (int i = 0; i < 4; ++i) {
            int q = tid + i * 256;
            int r = q >> 3, c8 = q & 7;
            uint4 v = *(const uint4*)(Pp + (size_t)r * 128 + pt * 64 + c8 * 8);
            *(uint4*)(&VT[r][c8 * 8]) = v;
        }
        __syncthreads();
#pragma unroll
        for (int tt = 0; tt < 2; ++tt) {
            bf16x8 pb[8];
#pragma unroll
            for (int n = 0; n < 8; ++n)
                pb[n] = *(const bf16x8*)(&VT[n * 16 + l15][tt * 32 + l4 * 8]);
#pragma unroll
            for (int m = 0; m < 2; ++m)
#pragma unroll
                for (int n = 0; n < 8; ++n)
                    acc[m][n] = __builtin_amdgcn_mfma_f32_16x16x32_bf16(qa[m][pt * 2 + tt], pb[n], acc[m][n], 0, 0, 0);
        }
        __syncthreads();
    }

    for (int kt2 = 0; kt2 < 2; ++kt2) {
#pragma unroll
        for (int i = 0; i < 4; ++i) {
            int q = tid + i * 256;
            int r = q >> 4, c8 = q & 15;
            uint4 v = *(const uint4*)(kn + base + (size_t)(c * 128 + kt2 * 64 + r) * 128 + c8 * 8);
            *(uint4*)(&KN[r][c8 * 8]) = v;
        }
#pragma unroll
        for (int i = 0; i < 4; ++i) {
            int q = tid + i * 256;
            int r = q >> 4, c16 = q & 15;
            uint4 v = *(const uint4*)(vr + base + (size_t)(c * 128 + kt2 * 64 + r) * 128 + c16 * 8);
            const u16* pv = (const u16*)&v;
#pragma unroll
            for (int j = 0; j < 8; ++j) VT[c16 * 8 + j][r] = pv[j];
        }
        __syncthreads();
        f32x4 sacc[2][4] = {};
#pragma unroll
        for (int t = 0; t < 4; ++t) {
            bf16x8 kb[4];
#pragma unroll
            for (int n = 0; n < 4; ++n)
                kb[n] = *(const bf16x8*)(&KN[n * 16 + l15][t * 32 + l4 * 8]);
#pragma unroll
            for (int m = 0; m < 2; ++m)
#pragma unroll
                for (int n = 0; n < 4; ++n)
                    sacc[m][n] = __builtin_amdgcn_mfma_f32_16x16x32_bf16(qa[m][t], kb[n], sacc[m][n], 0, 0, 0);
        }
#pragma unroll
        for (int m = 0; m < 2; ++m)
#pragma unroll
            for (int n = 0; n < 4; ++n)
#pragma unroll
                for (int r = 0; r < 4; ++r) {
                    int rowl = w * 32 + m * 16 + l4 * 4 + r;
                    int coll = n * 16 + l15;
                    int kl = kt2 * 64 + coll;
                    float val = (kl <= rowl) ? sacc[m][n][r] : 0.f;
                    __hip_bfloat16 hv = __float2bfloat16(val);
                    SC[rowl][coll] = *(u16*)&hv;
                }
#pragma unroll
        for (int t = 0; t < 2; ++t) {
            bf16x8 sa[2], vb[8];
#pragma unroll
            for (int m = 0; m < 2; ++m)
                sa[m] = *(const bf16x8*)(&SC[w * 32 + m * 16 + l15][t * 32 + l4 * 8]);
#pragma unroll
            for (int n = 0; n < 8; ++n)
                vb[n] = *(const bf16x8*)(&VT[n * 16 + l15][t * 32 + l4 * 8]);
#pragma unroll
            for (int m = 0; m < 2; ++m)
#pragma unroll
                for (int n = 0; n < 8; ++n)
                    acc[m][n] = __builtin_amdgcn_mfma_f32_16x16x32_bf16(sa[m], vb[n], acc[m][n], 0, 0, 0);
        }
        __syncthreads();
    }

#pragma unroll
    for (int m = 0; m < 2; ++m)
#pragma unroll
        for (int n = 0; n < 8; ++n)
#pragma unroll
            for (int r = 0; r < 4; ++r) {
                int srow = c * 128 + w * 32 + m * 16 + l4 * 4 + r;
                int d = n * 16 + l15;
                __hip_bfloat16 hv = __float2bfloat16(acc[m][n][r]);
                ao[(size_t)(b * S + srow) * D + h * 128 + d] = *(u16*)&hv;
            }
}

extern "C" void kernel_launch(void* const* d_in, const int* in_sizes, int n_in,
                              void* d_out, int out_size, void* d_ws, size_t ws_size,
                              hipStream_t stream)
{
    const float* hs = (const float*)d_in[0];
    const float* mask = (const float*)d_in[1];
    const int* pos = (const int*)d_in[2];
    const float* Wq = (const float*)d_in[3];
    const float* Wk = (const float*)d_in[4];
    const float* Wv = (const float*)d_in[5];
    const float* Wo = (const float*)d_in[6];
    const float* ncst = (const float*)d_in[7];
    float* out = (float*)d_out;

    char* ws = (char*)d_ws;
    size_t off = 0;
    auto alloc = [&](size_t bytes) {
        size_t o = off;
        off += (bytes + 255) & ~(size_t)255;
        return o;
    };
    u16* hs16 = (u16*)(ws + alloc((size_t)B * S * D * 2));
    u16* wqkv16 = (u16*)(ws + alloc((size_t)NQKV * D * 2));
    u16* wo16 = (u16*)(ws + alloc((size_t)D * D * 2));
    u16* tmpb = (u16*)(ws + alloc((size_t)B * S * NQKV * 2));
    u16* qn16 = (u16*)(ws + alloc((size_t)B * S * D * 2));
    u16* kn16 = (u16*)(ws + alloc((size_t)B * S * D * 2));
    u16* vr16 = (u16*)(ws + alloc((size_t)B * S * D * 2));
    float2* sc2 = (float2*)(ws + alloc((size_t)B * S * 32 * 8));
    float* keep = (float*)(ws + alloc((size_t)B * S * 4));
    float* counts = (float*)(ws + alloc((size_t)B * S * 4));
    float* expo = (float*)(ws + alloc(64));
    u16* ao16 = tmpb;
    u16* T16 = tmpb + (size_t)8388608;
    u16* P16 = tmpb + (size_t)16777216;

    fused_prep<<<1538, 256, 0, stream>>>(hs, Wq, Wk, Wv, Wo, mask, pos, ncst,
                                         hs16, wqkv16, wo16, sc2, keep, expo, counts);

    // fused QKV projection (bf16 out): 128x256, BK=64 (Wo geometry) -> 32x24 = 768
    // blocks = 3 exact rounds
    gemm64<128, 256, 2, 4, 4, 4, 1><<<768, 512, 0, stream>>>(
        hs16, wqkv16, nullptr, tmpb, NQKV, D, NQKV / 256);

    postproc_all<<<(B * S * H) / 4, 256, 0, stream>>>(tmpb, qn16, kn16, vr16,
                                                      sc2, keep, counts, expo);

    dim3 gc(S / 128, B * H);
    chunk_state<<<gc, 256, 0, stream>>>(kn16, vr16, T16);
    prefix_state<<<256, 256, 0, stream>>>(T16, P16);
    attn2<<<gc, 256, 0, stream>>>(qn16, kn16, vr16, P16, ao16);

    // output projection -> f32 out: 128x256, BK=64, 256 blocks (1 exact round)
    gemm64<128, 256, 2, 4, 4, 4, 0><<<256, 512, 0, stream>>>(
        ao16, wo16, out, nullptr, D, D, D / 256);
}

// Round 14
// 263.648 us; speedup vs baseline: 1.1564x; 1.1564x over previous
//
#include <hip/hip_runtime.h>
#include <hip/hip_bf16.h>

typedef __attribute__((ext_vector_type(8))) short bf16x8;
typedef __attribute__((ext_vector_type(4))) float f32x4;
typedef unsigned short u16;
typedef unsigned int u32;

constexpr int B = 2, S = 2048, D = 2048, H = 16, HD = 128, ROT = 64;
constexpr int NQKV = 3 * D;  // 6144

__device__ __forceinline__ void gload16(const u16* g, u16* l)
{
    __builtin_amdgcn_global_load_lds((const __attribute__((address_space(1))) void*)g,
                                     (__attribute__((address_space(3))) void*)l, 16, 0, 0);
}

__device__ __forceinline__ float bf2f(u32 lo16) { return __uint_as_float(lo16 << 16); }

// ---------------- fused prep: casts + rope table + keep/expo + counts ----------------
__global__ void fused_prep(const float* __restrict__ hs,
                           const float* __restrict__ Wq, const float* __restrict__ Wk,
                           const float* __restrict__ Wv, const float* __restrict__ Wo,
                           const float* __restrict__ mask, const int* __restrict__ pos,
                           const float* __restrict__ ncst,
                           u16* __restrict__ hs16, u16* __restrict__ wqkv16, u16* __restrict__ wo16,
                           float2* __restrict__ sc2, float* __restrict__ keep,
                           float* __restrict__ expo, float* __restrict__ counts)
{
    int bid = blockIdx.x, tid = threadIdx.x;
    if (bid < 1024) {
        const int total = 2097152 + 4 * 1048576;
        int idx = bid * 256 + tid;
        int stride = 1024 * 256;
        for (int i = idx; i < total; i += stride) {
            const float* src; u16* dst; int off;
            if (i < 2097152) { src = hs; dst = hs16; off = i; }
            else {
                int j = i - 2097152;
                int wsel = j >> 20; off = j & 1048575;
                src = wsel == 0 ? Wq : wsel == 1 ? Wk : wsel == 2 ? Wv : Wo;
                dst = wsel < 3 ? wqkv16 + (size_t)wsel * D * D : wo16;
            }
            float4 v = ((const float4*)src)[off];
            __hip_bfloat16 a = __float2bfloat16(v.x);
            __hip_bfloat16 b = __float2bfloat16(v.y);
            __hip_bfloat16 c = __float2bfloat16(v.z);
            __hip_bfloat16 d = __float2bfloat16(v.w);
            ushort4 o;
            o.x = *(u16*)&a; o.y = *(u16*)&b; o.z = *(u16*)&c; o.w = *(u16*)&d;
            ((ushort4*)dst)[off] = o;
        }
    } else if (bid < 1536) {
        int gid = (bid - 1024) * 256 + tid;
        int j = gid & 31;
        int bs = gid >> 5;
        float p = (float)pos[bs];
        float f = powf(10000.f, -(float)j / 32.f);
        float ang = p * f;
        sc2[gid] = make_float2(cosf(ang), sinf(ang));
        if (j == 0) keep[bs] = (mask[bs] == 0.f) ? 1.f : 0.f;
        if (gid < H) expo[gid] = 1.f / (1.f + expf(-ncst[gid]));
    } else {
        __shared__ float part[256];
        int b = bid - 1536, t = tid;
        float v[8];
        float s = 0.f;
        const float* mp = mask + b * S + t * 8;
#pragma unroll
        for (int i = 0; i < 8; ++i) { s += (mp[i] == 0.f) ? 1.f : 0.f; v[i] = s; }
        part[t] = s;
        __syncthreads();
        float off = 0.f;
        for (int j = 0; j < t; ++j) off += part[j];
        float* cp = counts + b * S + t * 8;
#pragma unroll
        for (int i = 0; i < 8; ++i) cp[i] = off + v[i];
    }
}

// =======================================================================
// BK=64 tiled bf16 B^T GEMM (R12 measured-best): double-buffered,
// prefetch-1 burst, counted vmcnt(CA+CB), 2 barriers/tile. 128B rows ->
// 8-slot XOR swizzle (slot16 ^= row&7) on BOTH pre-swizzled source and
// ds_read (rule 21): 16-lane frag reads are 2-way = free.
// Tile-geometry note (R13 lesson): 256x384 minimizes HBM panel re-reads
// (FETCH 108MB); smaller tiles tripled traffic and went BW-bound.
// =======================================================================

template <int CNT>
__device__ __forceinline__ void stage64(const u16* __restrict__ G, int K,
                                        int trow0, int kt, u16* lbuf, int tid)
{
#pragma unroll
    for (int l = 0; l < CNT; ++l) {
        int idx = l * 512 + tid;
        int row = idx >> 3;
        int slot = idx & 7;
        int col8 = slot ^ (row & 7);  // inverse-swizzled source
        const u16* g = G + (size_t)(trow0 + row) * K + kt * 64 + col8 * 8;
        u16* ld = lbuf + (size_t)(idx & ~63) * 8;  // wave-uniform base + lane*16B
        gload16(g, ld);
    }
}

template <int BM, int BN, int CA, int CB, int MR, int NR, int BF16OUT>
__global__ __launch_bounds__(512, 1) void gemm64(
    const u16* __restrict__ A, const u16* __restrict__ Bm,
    float* __restrict__ Cf, u16* __restrict__ Cb, int N, int K, int ntn)
{
    __shared__ u16 As[2 * BM * 64];
    __shared__ u16 Bs[2 * BN * 64];
    const int tid = threadIdx.x;
    const int lane = tid & 63;
    const int w = tid >> 6;
    const int wm = w >> 2;      // 0..1
    const int wn = w & 3;       // 0..3
    const int l15 = lane & 15, l4 = lane >> 4;

    // bijective XCD-aware swizzle (nwg % 8 == 0)
    int nwg = gridDim.x;
    int bid = blockIdx.x;
    int cpx = nwg >> 3;
    int sbid = (bid & 7) * cpx + (bid >> 3);
    int bm = sbid / ntn, bn = sbid % ntn;
    const int bmrow = bm * BM, bnrow = bn * BN;

    f32x4 acc[MR][NR] = {};
    const int nk = K >> 6;

    stage64<CA>(A, K, bmrow, 0, &As[0], tid);
    stage64<CB>(Bm, K, bnrow, 0, &Bs[0], tid);

    for (int t = 0; t < nk; ++t) {
        const u16* ab = &As[(t & 1) * BM * 64];
        const u16* bb = &Bs[(t & 1) * BN * 64];
        if (t + 1 < nk) {
            stage64<CA>(A, K, bmrow, t + 1, &As[((t + 1) & 1) * BM * 64], tid);
            stage64<CB>(Bm, K, bnrow, t + 1, &Bs[((t + 1) & 1) * BN * 64], tid);
            asm volatile("s_waitcnt vmcnt(%0)" :: "i"(CA + CB) : "memory");
        } else {
            asm volatile("s_waitcnt vmcnt(0)" ::: "memory");
        }
        __builtin_amdgcn_sched_barrier(0);
        __builtin_amdgcn_s_barrier();  // tile t resident for all waves

#pragma unroll
        for (int tt = 0; tt < 2; ++tt) {
            bf16x8 af[MR];
#pragma unroll
            for (int i = 0; i < MR; ++i) {
                int row = wm * (BM / 2) + i * 16 + l15;
                int slot = (tt * 4 + l4) ^ (row & 7);
                af[i] = *(const bf16x8*)(ab + row * 64 + slot * 8);
            }
#pragma unroll
            for (int n = 0; n < NR; ++n) {
                int brow = wn * (BN / 4) + n * 16 + l15;
                int bslot = (tt * 4 + l4) ^ (brow & 7);
                bf16x8 bf = *(const bf16x8*)(bb + brow * 64 + bslot * 8);
                __builtin_amdgcn_s_setprio(1);
#pragma unroll
                for (int i = 0; i < MR; ++i)
                    acc[i][n] = __builtin_amdgcn_mfma_f32_16x16x32_bf16(af[i], bf, acc[i][n], 0, 0, 0);
                __builtin_amdgcn_s_setprio(0);
            }
        }
        __builtin_amdgcn_sched_barrier(0);
        __builtin_amdgcn_s_barrier();  // all reads done before next-iter stages
    }

    // epilogue
#pragma unroll
    for (int i = 0; i < MR; ++i) {
        int row = bmrow + wm * (BM / 2) + i * 16 + l4 * 4;
#pragma unroll
        for (int n = 0; n < NR; ++n) {
            int col = bnrow + wn * (BN / 4) + n * 16 + l15;
            f32x4 v = acc[i][n];
#pragma unroll
            for (int r = 0; r < 4; ++r) {
                if (BF16OUT) {
                    __hip_bfloat16 hv = __float2bfloat16(v[r]);
                    Cb[(size_t)(row + r) * N + col] = *(u16*)&hv;
                } else {
                    Cf[(size_t)(row + r) * N + col] = v[r];
                }
            }
        }
    }
}

// ---------------- fused postproc: RoPE + norm (q,k), count-scale (v) ----------------
__global__ void postproc_all(const u16* __restrict__ tmpb,
                             u16* __restrict__ qn, u16* __restrict__ kn, u16* __restrict__ vr,
                             const float2* __restrict__ sc2,
                             const float* __restrict__ keep, const float* __restrict__ counts,
                             const float* __restrict__ expo)
{
    int gw = (blockIdx.x * blockDim.x + threadIdx.x) >> 6;
    int lane = threadIdx.x & 63;
    if (gw >= B * S * H) return;
    int h = gw % H;
    int sb = gw / H;
    int s = sb % S;
    int b = sb / S;
    const u16* rowp = tmpb + (size_t)(b * S + s) * NQKV;
    u32 qv = *(const u32*)(rowp + h * 128 + lane * 2);
    u32 kv = *(const u32*)(rowp + D + h * 128 + lane * 2);
    u32 vv = *(const u32*)(rowp + 2 * D + h * 128 + lane * 2);
    float q0 = bf2f(qv & 0xffff), q1 = bf2f(qv >> 16);
    float k0 = bf2f(kv & 0xffff), k1 = bf2f(kv >> 16);
    float v0 = bf2f(vv & 0xffff), v1 = bf2f(vv >> 16);
    if (lane < 32) {
        float2 cs = sc2[(b * S + s) * 32 + lane];
        float nq0 = q0 * cs.x - q1 * cs.y, nq1 = q1 * cs.x + q0 * cs.y;
        float nk0 = k0 * cs.x - k1 * cs.y, nk1 = k1 * cs.x + k0 * cs.y;
        q0 = nq0; q1 = nq1; k0 = nk0; k1 = nk1;
    }
    float sq = q0 * q0 + q1 * q1;
    float sk = k0 * k0 + k1 * k1;
#pragma unroll
    for (int o = 1; o < 64; o <<= 1) {
        sq += __shfl_xor(sq, o, 64);
        sk += __shfl_xor(sk, o, 64);
    }
    float kf = keep[b * S + s];
    float scq = kf / fmaxf(sqrtf(sq), 1e-12f);
    float sck = kf / fmaxf(sqrtf(sk), 1e-12f);
    float cnt = counts[b * S + s];
    float e = expo[h];
    float scv = kf / fmaxf(powf(cnt, e), 1.0f);

    __hip_bfloat16 a0 = __float2bfloat16(q0 * scq), a1 = __float2bfloat16(q1 * scq);
    __hip_bfloat16 b0 = __float2bfloat16(k0 * sck), b1 = __float2bfloat16(k1 * sck);
    __hip_bfloat16 c0 = __float2bfloat16(v0 * scv), c1 = __float2bfloat16(v1 * scv);
    size_t obase = ((size_t)(b * H + h) * S + s) * 128 + lane * 2;
    *(u32*)(qn + obase) = (u32)*(u16*)&a0 | ((u32)*(u16*)&a1 << 16);
    *(u32*)(kn + obase) = (u32)*(u16*)&b0 | ((u32)*(u16*)&b1 << 16);
    *(u32*)(vr + obase) = (u32)*(u16*)&c0 | ((u32)*(u16*)&c1 << 16);
}

// ---------------- chunk state: T_c[d][d'] = sum_{k in chunk} v[k,d] * kn[k,d'] ----------------
__global__ __launch_bounds__(256) void chunk_state(
    const u16* __restrict__ kn, const u16* __restrict__ vr, u16* __restrict__ T16)
{
    __shared__ u16 As[128][72];
    __shared__ u16 Bs[128][72];
    int tid = threadIdx.x, lane = tid & 63, w = tid >> 6;
    int wm = w >> 1, wn = w & 1;
    int c = blockIdx.x, bh = blockIdx.y;
    const int l15 = lane & 15, l4 = lane >> 4;
    size_t base = (size_t)bh * S * 128;
    f32x4 acc[4][4] = {};

    for (int t = 0; t < 2; ++t) {
#pragma unroll
        for (int i = 0; i < 4; ++i) {
            int q = tid + i * 256;
            int r = q >> 4, c16 = q & 15;
            uint4 v = *(const uint4*)(vr + base + (size_t)(c * 128 + t * 64 + r) * 128 + c16 * 8);
            const u16* pv = (const u16*)&v;
#pragma unroll
            for (int j = 0; j < 8; ++j) As[c16 * 8 + j][r] = pv[j];
        }
#pragma unroll
        for (int i = 0; i < 4; ++i) {
            int q = tid + i * 256;
            int r = q >> 4, c16 = q & 15;
            uint4 v = *(const uint4*)(kn + base + (size_t)(c * 128 + t * 64 + r) * 128 + c16 * 8);
            const u16* pv = (const u16*)&v;
#pragma unroll
            for (int j = 0; j < 8; ++j) Bs[c16 * 8 + j][r] = pv[j];
        }
        __syncthreads();
#pragma unroll
        for (int tt = 0; tt < 2; ++tt) {
            bf16x8 a[4], b[4];
#pragma unroll
            for (int m = 0; m < 4; ++m)
                a[m] = *(const bf16x8*)(&As[wm * 64 + m * 16 + l15][tt * 32 + l4 * 8]);
#pragma unroll
            for (int n = 0; n < 4; ++n)
                b[n] = *(const bf16x8*)(&Bs[wn * 64 + n * 16 + l15][tt * 32 + l4 * 8]);
#pragma unroll
            for (int m = 0; m < 4; ++m)
#pragma unroll
                for (int n = 0; n < 4; ++n)
                    acc[m][n] = __builtin_amdgcn_mfma_f32_16x16x32_bf16(a[m], b[n], acc[m][n], 0, 0, 0);
        }
        __syncthreads();
    }
#pragma unroll
    for (int m = 0; m < 4; ++m) {
        int row = wm * 64 + m * 16 + l4 * 4;
#pragma unroll
        for (int n = 0; n < 4; ++n) {
            int col = wn * 64 + n * 16 + l15;
#pragma unroll
            for (int r = 0; r < 4; ++r) {
                __hip_bfloat16 hv = __float2bfloat16(acc[m][n][r]);
                T16[((size_t)(bh * 16 + c) * 128 + row + r) * 128 + col] = *(u16*)&hv;
            }
        }
    }
}

// ---------------- exclusive prefix over chunks ----------------
__global__ void prefix_state(const u16* __restrict__ T16, u16* __restrict__ P16)
{
    int g = blockIdx.x * blockDim.x + threadIdx.x;
    int bh = g >> 11;
    int i8 = (g & 2047) * 8;
    const u16* tp = T16 + (size_t)bh * 16 * 16384 + i8;
    u16* pp = P16 + (size_t)bh * 16 * 16384 + i8;
    float run[8] = {};
    for (int c = 0; c < 16; ++c) {
        u16 ob[8];
#pragma unroll
        for (int j = 0; j < 8; ++j) { __hip_bfloat16 hv = __float2bfloat16(run[j]); ob[j] = *(u16*)&hv; }
        *(uint4*)(pp + (size_t)c * 16384) = *(uint4*)ob;
        uint4 tv = *(const uint4*)(tp + (size_t)c * 16384);
        const u16* tvp = (const u16*)&tv;
#pragma unroll
        for (int j = 0; j < 8; ++j) run[j] += bf2f(tvp[j]);
    }
}

// ---------------- chunked attention: out_c = qn_c . P_c + causal_intra ----------------
__global__ __launch_bounds__(256, 2) void attn2(
    const u16* __restrict__ qn, const u16* __restrict__ kn,
    const u16* __restrict__ vr, const u16* __restrict__ P16, u16* __restrict__ ao)
{
    __shared__ u16 KN[64][136];
    __shared__ u16 VT[128][72];
    __shared__ u16 SC[128][72];
    int tid = threadIdx.x, lane = tid & 63, w = tid >> 6;
    int c = blockIdx.x, bh = blockIdx.y;
    int b = bh >> 4, h = bh & 15;
    const int l15 = lane & 15, l4 = lane >> 4;
    size_t base = (size_t)bh * S * 128;
    const u16* Pp = P16 + (size_t)(bh * 16 + c) * 16384;

    bf16x8 qa[2][4];
#pragma unroll
    for (int m = 0; m < 2; ++m)
#pragma unroll
        for (int t = 0; t < 4; ++t) {
            int row = c * 128 + w * 32 + m * 16 + l15;
            qa[m][t] = *(const bf16x8*)(qn + base + (size_t)row * 128 + t * 32 + l4 * 8);
        }

    f32x4 acc[2][8] = {};

#pragma unroll
    for (int pt = 0; pt < 2; ++pt) {
#pragma unroll
        for (int i = 0; i < 4; ++i) {
            int q = tid + i * 256;
            int r = q >> 3, c8 = q & 7;
            uint4 v = *(const uint4*)(Pp + (size_t)r * 128 + pt * 64 + c8 * 8);
            *(uint4*)(&VT[r][c8 * 8]) = v;
        }
        __syncthreads();
#pragma unroll
        for (int tt = 0; tt < 2; ++tt) {
            bf16x8 pb[8];
#pragma unroll
            for (int n = 0; n < 8; ++n)
                pb[n] = *(const bf16x8*)(&VT[n * 16 + l15][tt * 32 + l4 * 8]);
#pragma unroll
            for (int m = 0; m < 2; ++m)
#pragma unroll
                for (int n = 0; n < 8; ++n)
                    acc[m][n] = __builtin_amdgcn_mfma_f32_16x16x32_bf16(qa[m][pt * 2 + tt], pb[n], acc[m][n], 0, 0, 0);
        }
        __syncthreads();
    }

    for (int kt2 = 0; kt2 < 2; ++kt2) {
#pragma unroll
        for (int i = 0; i < 4; ++i) {
            int q = tid + i * 256;
            int r = q >> 4, c8 = q & 15;
            uint4 v = *(const uint4*)(kn + base + (size_t)(c * 128 + kt2 * 64 + r) * 128 + c8 * 8);
            *(uint4*)(&KN[r][c8 * 8]) = v;
        }
#pragma unroll
        for (int i = 0; i < 4; ++i) {
            int q = tid + i * 256;
            int r = q >> 4, c16 = q & 15;
            uint4 v = *(const uint4*)(vr + base + (size_t)(c * 128 + kt2 * 64 + r) * 128 + c16 * 8);
            const u16* pv = (const u16*)&v;
#pragma unroll
            for (int j = 0; j < 8; ++j) VT[c16 * 8 + j][r] = pv[j];
        }
        __syncthreads();
        f32x4 sacc[2][4] = {};
#pragma unroll
        for (int t = 0; t < 4; ++t) {
            bf16x8 kb[4];
#pragma unroll
            for (int n = 0; n < 4; ++n)
                kb[n] = *(const bf16x8*)(&KN[n * 16 + l15][t * 32 + l4 * 8]);
#pragma unroll
            for (int m = 0; m < 2; ++m)
#pragma unroll
                for (int n = 0; n < 4; ++n)
                    sacc[m][n] = __builtin_amdgcn_mfma_f32_16x16x32_bf16(qa[m][t], kb[n], sacc[m][n], 0, 0, 0);
        }
#pragma unroll
        for (int m = 0; m < 2; ++m)
#pragma unroll
            for (int n = 0; n < 4; ++n)
#pragma unroll
                for (int r = 0; r < 4; ++r) {
                    int rowl = w * 32 + m * 16 + l4 * 4 + r;
                    int coll = n * 16 + l15;
                    int kl = kt2 * 64 + coll;
                    float val = (kl <= rowl) ? sacc[m][n][r] : 0.f;
                    __hip_bfloat16 hv = __float2bfloat16(val);
                    SC[rowl][coll] = *(u16*)&hv;
                }
#pragma unroll
        for (int t = 0; t < 2; ++t) {
            bf16x8 sa[2], vb[8];
#pragma unroll
            for (int m = 0; m < 2; ++m)
                sa[m] = *(const bf16x8*)(&SC[w * 32 + m * 16 + l15][t * 32 + l4 * 8]);
#pragma unroll
            for (int n = 0; n < 8; ++n)
                vb[n] = *(const bf16x8*)(&VT[n * 16 + l15][t * 32 + l4 * 8]);
#pragma unroll
            for (int m = 0; m < 2; ++m)
#pragma unroll
                for (int n = 0; n < 8; ++n)
                    acc[m][n] = __builtin_amdgcn_mfma_f32_16x16x32_bf16(sa[m], vb[n], acc[m][n], 0, 0, 0);
        }
        __syncthreads();
    }

#pragma unroll
    for (int m = 0; m < 2; ++m)
#pragma unroll
        for (int n = 0; n < 8; ++n)
#pragma unroll
            for (int r = 0; r < 4; ++r) {
                int srow = c * 128 + w * 32 + m * 16 + l4 * 4 + r;
                int d = n * 16 + l15;
                __hip_bfloat16 hv = __float2bfloat16(acc[m][n][r]);
                ao[(size_t)(b * S + srow) * D + h * 128 + d] = *(u16*)&hv;
            }
}

extern "C" void kernel_launch(void* const* d_in, const int* in_sizes, int n_in,
                              void* d_out, int out_size, void* d_ws, size_t ws_size,
                              hipStream_t stream)
{
    const float* hs = (const float*)d_in[0];
    const float* mask = (const float*)d_in[1];
    const int* pos = (const int*)d_in[2];
    const float* Wq = (const float*)d_in[3];
    const float* Wk = (const float*)d_in[4];
    const float* Wv = (const float*)d_in[5];
    const float* Wo = (const float*)d_in[6];
    const float* ncst = (const float*)d_in[7];
    float* out = (float*)d_out;

    char* ws = (char*)d_ws;
    size_t off = 0;
    auto alloc = [&](size_t bytes) {
        size_t o = off;
        off += (bytes + 255) & ~(size_t)255;
        return o;
    };
    u16* hs16 = (u16*)(ws + alloc((size_t)B * S * D * 2));
    u16* wqkv16 = (u16*)(ws + alloc((size_t)NQKV * D * 2));
    u16* wo16 = (u16*)(ws + alloc((size_t)D * D * 2));
    u16* tmpb = (u16*)(ws + alloc((size_t)B * S * NQKV * 2));
    u16* qn16 = (u16*)(ws + alloc((size_t)B * S * D * 2));
    u16* kn16 = (u16*)(ws + alloc((size_t)B * S * D * 2));
    u16* vr16 = (u16*)(ws + alloc((size_t)B * S * D * 2));
    float2* sc2 = (float2*)(ws + alloc((size_t)B * S * 32 * 8));
    float* keep = (float*)(ws + alloc((size_t)B * S * 4));
    float* counts = (float*)(ws + alloc((size_t)B * S * 4));
    float* expo = (float*)(ws + alloc(64));
    u16* ao16 = tmpb;
    u16* T16 = tmpb + (size_t)8388608;
    u16* P16 = tmpb + (size_t)16777216;

    fused_prep<<<1538, 256, 0, stream>>>(hs, Wq, Wk, Wv, Wo, mask, pos, ncst,
                                         hs16, wqkv16, wo16, sc2, keep, expo, counts);

    // fused QKV projection (bf16 out): 256x384, BK=64, 256 blocks (1 exact round)
    gemm64<256, 384, 4, 6, 8, 6, 1><<<256, 512, 0, stream>>>(
        hs16, wqkv16, nullptr, tmpb, NQKV, D, NQKV / 384);

    postproc_all<<<(B * S * H) / 4, 256, 0, stream>>>(tmpb, qn16, kn16, vr16,
                                                      sc2, keep, counts, expo);

    dim3 gc(S / 128, B * H);
    chunk_state<<<gc, 256, 0, stream>>>(kn16, vr16, T16);
    prefix_state<<<256, 256, 0, stream>>>(T16, P16);
    attn2<<<gc, 256, 0, stream>>>(qn16, kn16, vr16, P16, ao16);

    // output projection -> f32 out: 128x256, BK=64, 256 blocks (1 exact round)
    gemm64<128, 256, 2, 4, 4, 4, 0><<<256, 512, 0, stream>>>(
        ao16, wo16, out, nullptr, D, D, D / 256);
}